// Round 4
// baseline (199.068 us; speedup 1.0000x reference)
//
#include <hip/hip_runtime.h>

#define DF 128     // feature dim
#define KX 256     // extended GEMM K: [Agg | feat]
#define CAP 16     // bucket capacity per node = one 64B cache line
#define GR 64      // GEMM rows per block
#define PBLK 1024  // placement blocks

typedef __attribute__((ext_vector_type(8))) short short8;   // 8 bf16 (4 VGPRs)
typedef __attribute__((ext_vector_type(4))) float v4f;      // MFMA accumulator

__device__ __forceinline__ unsigned short f2bf(float x) {
    unsigned u = __float_as_uint(x);
    unsigned r = (u + 0x7FFFu + ((u >> 16) & 1u)) >> 16;    // RNE
    return (unsigned short)r;
}
__device__ __forceinline__ float bf2f(unsigned short h) {
    return __uint_as_float((unsigned)h << 16);
}
__device__ __forceinline__ unsigned pack2(float a, float b) {
    return (unsigned)f2bf(a) | ((unsigned)f2bf(b) << 16);
}

// ---------------------------------------------------------------------------
// prep: b0 = dtype detect + hdr init + zero Fbf sentinel row M;
// b1..128 = build Bt2[n][k] (128 x 256 bf16): k<128 -> Wn[k][n], else Ws[k-128][n];
// next nzb blocks = zero counts; remaining blocks = feat f32 -> Fbf bf16.
// hdr[0]=is32, hdr[1]=overflow count.
// ---------------------------------------------------------------------------
__global__ __launch_bounds__(256) void prep_kernel(
    const int* __restrict__ idx32, int nE, int* __restrict__ hdr,
    const float* __restrict__ Wn, const float* __restrict__ Ws,
    unsigned short* __restrict__ Bt2, int* __restrict__ counts, int cnt_ints,
    const float* __restrict__ feat, unsigned short* __restrict__ Fbf,
    int M, int nzb)
{
    const int b = blockIdx.x;
    const int t = threadIdx.x;
    if (b == 0) {
        __shared__ int sh;
        if (t == 0) sh = 0;
        __syncthreads();
        int found = 0;
        for (int i = t; i < 2048 && i < nE; i += 256)
            if (idx32[2 * i + 1] != 0) found = 1;
        if (found) sh = 1;                 // benign race, any writer sets 1
        __syncthreads();
        if (t == 0) { hdr[0] = sh; hdr[1] = 0; }
        // zero sentinel row Fbf[M] (256B = 64 uints)
        if (t < 64)
            reinterpret_cast<unsigned*>(Fbf + (size_t)M * DF)[t] = 0u;
    } else if (b <= 128) {
        int idx = (b - 1) * 256 + t;       // 0..32767 over [n][k], k in [0,256)
        int n = idx >> 8, k = idx & 255;
        float v = (k < DF) ? Wn[(size_t)k * DF + n]
                           : Ws[(size_t)(k - DF) * DF + n];
        Bt2[idx] = f2bf(v);
    } else if (b <= 128 + nzb) {
        int off = ((b - 129) * 256 + t) * 4;   // int index, int4 stores
        if (off < cnt_ints)
            *reinterpret_cast<int4*>(counts + off) = make_int4(0, 0, 0, 0);
    } else {
        // feat -> bf16 conversion: 8 floats/thread, contiguous
        const long long base = ((long long)(b - 129 - nzb) * 2048 + t * 8);
        const long long total = (long long)M * DF;
        if (base + 8 <= total) {
            float4 v0 = *reinterpret_cast<const float4*>(feat + base);
            float4 v1 = *reinterpret_cast<const float4*>(feat + base + 4);
            uint4 pk;
            pk.x = pack2(v0.x, v0.y);
            pk.y = pack2(v0.z, v0.w);
            pk.z = pack2(v1.x, v1.y);
            pk.w = pack2(v1.z, v1.w);
            *reinterpret_cast<uint4*>(Fbf + base) = pk;
        }
    }
}

// ---------------------------------------------------------------------------
// placement: pos = counts[dst]++; bucket slot or overflow list. Standalone
// dispatch so its true cost is visible in the profile.
// ---------------------------------------------------------------------------
__global__ __launch_bounds__(256) void place_kernel(
    const void* __restrict__ src, const void* __restrict__ dst, int nE,
    int* __restrict__ hdr, int* __restrict__ counts, int* __restrict__ buckets,
    int2* __restrict__ ovf)
{
    const int t = threadIdx.x;
    const int is32 = hdr[0];
    const int stride = PBLK * 256;
    if (is32) {
        const int* sp = (const int*)src;
        const int* dp = (const int*)dst;
        for (int e = blockIdx.x * 256 + t; e < nE; e += stride) {
            int s = sp[e], d = dp[e];
            int pos = atomicAdd(&counts[d], 1);
            if (pos < CAP) {
                buckets[(size_t)d * CAP + pos] = s;
            } else {
                int oi = atomicAdd(&hdr[1], 1);
                ovf[oi] = make_int2(s, d);
            }
        }
    } else {
        const long long* sp = (const long long*)src;
        const long long* dp = (const long long*)dst;
        for (int e = blockIdx.x * 256 + t; e < nE; e += stride) {
            int s = (int)sp[e], d = (int)dp[e];
            int pos = atomicAdd(&counts[d], 1);
            if (pos < CAP) {
                buckets[(size_t)d * CAP + pos] = s;
            } else {
                int oi = atomicAdd(&hdr[1], 1);
                ovf[oi] = make_int2(s, d);
            }
        }
    }
}

// ---------------------------------------------------------------------------
// agg_gemm: per 64-node tile, (1) aggregate neighbor Fbf rows (branch-free
// sentinel bursts, f32 accum) + stage self row -> As[64][Agg|feat] bf16,
// (2) K=256 MFMA: out = [Agg|feat] @ [Wn;Ws] + b, written ONCE (no RMW,
// no Ybf). Random-read latency of (1) overlaps MFMA of other blocks.
// ---------------------------------------------------------------------------
__global__ __launch_bounds__(256) void agg_gemm_kernel(
    const unsigned short* __restrict__ Fbf, const unsigned short* __restrict__ Bt2,
    const float* __restrict__ bias, float* __restrict__ out, int M,
    const int* __restrict__ counts, const int* __restrict__ buckets,
    const int* __restrict__ hdr, const int2* __restrict__ ovf)
{
    __shared__ unsigned short As[GR][KX + 8];   // [Agg(128) | self(128)] bf16

    const int t = threadIdx.x;
    const int block_row = blockIdx.x * GR;

    const int wave = t >> 6;
    const int lane = t & 63;
    const int nl   = lane & 15;
    const int quad = lane >> 4;

    // ---- preload B fragments first (independent, L2-hot, arrive under agg) ----
    const int n0 = wave * 32;
    short8 bfrag[2][8];
#pragma unroll
    for (int ct = 0; ct < 2; ct++)
#pragma unroll
        for (int kk = 0; kk < 8; kk++)
            bfrag[ct][kk] = *reinterpret_cast<const short8*>(
                Bt2 + (size_t)(n0 + ct * 16 + nl) * KX + kk * 32 + quad * 8);
    float bcol[2];
#pragma unroll
    for (int ct = 0; ct < 2; ct++)
        bcol[ct] = bias[n0 + ct * 16 + nl];

    // ---- phase 1: aggregate 4 nodes per 16-lane group ----
    {
        const int gi = t >> 4;          // group 0..15
        const int li = t & 15;          // lane in group
        const size_t lo = (size_t)li * 8;   // bf16 elems (16B per lane)
        const int n_ovf = hdr[1];

#define LDF(s) (*reinterpret_cast<const uint4*>(Fbf + (size_t)(s) * DF + lo))
#define ACC8(Y) do { \
        a0 += bf2f((unsigned short)((Y).x)); a1 += bf2f((unsigned short)((Y).x >> 16)); \
        a2 += bf2f((unsigned short)((Y).y)); a3 += bf2f((unsigned short)((Y).y >> 16)); \
        a4 += bf2f((unsigned short)((Y).z)); a5 += bf2f((unsigned short)((Y).z >> 16)); \
        a6 += bf2f((unsigned short)((Y).w)); a7 += bf2f((unsigned short)((Y).w >> 16)); \
    } while (0)

#pragma unroll
        for (int j = 0; j < 4; j++) {
            const int r_local = gi * 4 + j;
            const int grow = block_row + r_local;
            const int deg_raw = (grow < M) ? counts[grow] : 0;
            const int deg = min(deg_raw, CAP);
            const int* b = buckets + (size_t)((grow < M) ? grow : 0) * CAP;

            float a0 = 0.f, a1 = 0.f, a2 = 0.f, a3 = 0.f;
            float a4 = 0.f, a5 = 0.f, a6 = 0.f, a7 = 0.f;

            // slots 0..7, sentinel-selected, unconditional burst
            int4 sa = *reinterpret_cast<const int4*>(b);
            int4 sb = *reinterpret_cast<const int4*>(b + 4);
            const int i0 = (0 < deg) ? sa.x : M;
            const int i1 = (1 < deg) ? sa.y : M;
            const int i2 = (2 < deg) ? sa.z : M;
            const int i3 = (3 < deg) ? sa.w : M;
            const int i4 = (4 < deg) ? sb.x : M;
            const int i5 = (5 < deg) ? sb.y : M;
            const int i6 = (6 < deg) ? sb.z : M;
            const int i7 = (7 < deg) ? sb.w : M;
            uint4 y0 = LDF(i0);
            uint4 y1 = LDF(i1);
            uint4 y2 = LDF(i2);
            uint4 y3 = LDF(i3);
            uint4 y4 = LDF(i4);
            uint4 y5 = LDF(i5);
            uint4 y6 = LDF(i6);
            uint4 y7 = LDF(i7);
            // self row rides in the same burst
            uint4 sf = LDF((grow < M) ? grow : M);
            ACC8(y0); ACC8(y1); ACC8(y2); ACC8(y3);
            ACC8(y4); ACC8(y5); ACC8(y6); ACC8(y7);

            if (deg > 8) {
                int4 sc = *reinterpret_cast<const int4*>(b + 8);
                int4 sd = *reinterpret_cast<const int4*>(b + 12);
                const int j0 = ( 8 < deg) ? sc.x : M;
                const int j1 = ( 9 < deg) ? sc.y : M;
                const int j2 = (10 < deg) ? sc.z : M;
                const int j3 = (11 < deg) ? sc.w : M;
                const int j4 = (12 < deg) ? sd.x : M;
                const int j5 = (13 < deg) ? sd.y : M;
                const int j6 = (14 < deg) ? sd.z : M;
                const int j7 = (15 < deg) ? sd.w : M;
                uint4 z0 = LDF(j0);
                uint4 z1 = LDF(j1);
                uint4 z2 = LDF(j2);
                uint4 z3 = LDF(j3);
                uint4 z4 = LDF(j4);
                uint4 z5 = LDF(j5);
                uint4 z6 = LDF(j6);
                uint4 z7 = LDF(j7);
                ACC8(z0); ACC8(z1); ACC8(z2); ACC8(z3);
                ACC8(z4); ACC8(z5); ACC8(z6); ACC8(z7);
            }

            // rare: overflow edges for this node (list is tiny)
            if (deg_raw > CAP) {
                for (int i = 0; i < n_ovf; i++) {
                    int2 sd2 = ovf[i];
                    if (sd2.y == grow) {
                        uint4 y = LDF(sd2.x);
                        ACC8(y);
                    }
                }
            }

            // write Agg (rounded bf16) and self halves of the A row
            uint4 pk;
            pk.x = pack2(a0, a1);
            pk.y = pack2(a2, a3);
            pk.z = pack2(a4, a5);
            pk.w = pack2(a6, a7);
            *reinterpret_cast<uint4*>(&As[r_local][lo])      = pk;
            *reinterpret_cast<uint4*>(&As[r_local][DF + lo]) = sf;
        }
#undef LDF
#undef ACC8
    }

    __syncthreads();

    // ---- phase 2: K=256 MFMA, direct out store (write-once) ----
#pragma unroll
    for (int rt = 0; rt < 4; rt++) {
        short8 afrag[8];
#pragma unroll
        for (int kk = 0; kk < 8; kk++)
            afrag[kk] = *reinterpret_cast<const short8*>(
                &As[rt * 16 + nl][kk * 32 + quad * 8]);
#pragma unroll
        for (int ct = 0; ct < 2; ct++) {
            v4f acc = {0.f, 0.f, 0.f, 0.f};
#pragma unroll
            for (int kk = 0; kk < 8; kk++)
                acc = __builtin_amdgcn_mfma_f32_16x16x32_bf16(
                    afrag[kk], bfrag[ct][kk], acc, 0, 0, 0);
            const int n = n0 + ct * 16 + nl;
            const int lrow = rt * 16 + quad * 4;
#pragma unroll
            for (int r = 0; r < 4; r++) {
                const int grow = block_row + lrow + r;
                if (grow < M)
                    out[(size_t)grow * DF + n] = acc[r] + bcol[ct];
            }
        }
    }
}

extern "C" void kernel_launch(void* const* d_in, const int* in_sizes, int n_in,
                              void* d_out, int out_size, void* d_ws, size_t ws_size,
                              hipStream_t stream) {
    const float* feat = (const float*)d_in[0];
    const void*  src  = d_in[1];
    const void*  dst  = d_in[2];
    const float* Wn   = (const float*)d_in[3];
    const float* bias = (const float*)d_in[4];
    const float* Wsf  = (const float*)d_in[5];
    float* out = (float*)d_out;

    const int M  = in_sizes[0] / DF;   // 100000
    const int nE = in_sizes[1];        // 600000

    // workspace: [hdr 256B][counts][buckets][Bt2 64KB][Fbf (M+1 rows)][ovf]
    const size_t cnt_off   = 256;
    const size_t cnt_bytes = (((size_t)(M + 64) * 4) + 255) & ~(size_t)255;
    const size_t bkt_off   = cnt_off + cnt_bytes;
    const size_t bkt_bytes = (size_t)M * CAP * sizeof(int);
    const size_t bt_off    = (bkt_off + bkt_bytes + 255) & ~(size_t)255;
    const size_t bt_bytes  = (size_t)DF * KX * sizeof(unsigned short);
    const size_t f_off     = bt_off + bt_bytes;
    const size_t f_bytes   = (size_t)(M + 1) * DF * sizeof(unsigned short);
    const size_t ovf_off   = (f_off + f_bytes + 255) & ~(size_t)255;

    int*            hdr     = (int*)d_ws;
    int*            counts  = (int*)((char*)d_ws + cnt_off);
    int*            buckets = (int*)((char*)d_ws + bkt_off);
    unsigned short* Bt2     = (unsigned short*)((char*)d_ws + bt_off);
    unsigned short* Fbf     = (unsigned short*)((char*)d_ws + f_off);
    int2*           ovf     = (int2*)((char*)d_ws + ovf_off);

    const int cnt_ints = (int)(cnt_bytes / 4);
    const int nzb = (cnt_ints + 1023) / 1024;
    const long long total = (long long)M * DF;
    const int nconv = (int)((total + 2047) / 2048);

    prep_kernel<<<1 + 128 + nzb + nconv, 256, 0, stream>>>(
        (const int*)src, nE, hdr, Wn, Wsf, Bt2, counts, cnt_ints,
        feat, Fbf, M, nzb);

    place_kernel<<<PBLK, 256, 0, stream>>>(
        src, dst, nE, hdr, counts, buckets, ovf);

    const int gemm_blocks = (M + GR - 1) / GR;
    agg_gemm_kernel<<<gemm_blocks, 256, 0, stream>>>(
        Fbf, Bt2, bias, out, M, counts, buckets, hdr, ovf);
}

// Round 5
// 188.229 us; speedup vs baseline: 1.0576x; 1.0576x over previous
//
#include <hip/hip_runtime.h>

#define DF 128     // feature dim
#define KX 256     // extended GEMM K: [Agg | feat]
#define CAP 16     // bucket capacity per node = one 64B cache line
#define GR 64      // GEMM rows per block

typedef __attribute__((ext_vector_type(8))) short short8;   // 8 bf16 (4 VGPRs)
typedef __attribute__((ext_vector_type(4))) float v4f;      // MFMA accumulator

__device__ __forceinline__ unsigned short f2bf(float x) {
    unsigned u = __float_as_uint(x);
    unsigned r = (u + 0x7FFFu + ((u >> 16) & 1u)) >> 16;    // RNE
    return (unsigned short)r;
}
__device__ __forceinline__ float bf2f(unsigned short h) {
    return __uint_as_float((unsigned)h << 16);
}
__device__ __forceinline__ unsigned pack2(float a, float b) {
    return (unsigned)f2bf(a) | ((unsigned)f2bf(b) << 16);
}

// ---------------------------------------------------------------------------
// mega: one dispatch fusing three independent jobs (block-specialized):
//   blocks [0, NPB)            : edge placement, 1 edge/thread. Latency-bound.
//   blocks [NPB, NPB+128)      : Bt2[n][k] build (128 x 256 bf16 weights^T).
//   blocks [NPB+128, ...)      : feat f32 -> Fbf bf16 stream + zero sentinel
//                                row M. BW-bound; overlaps placement latency.
// Requires hdr+counts pre-zeroed (hipMemsetAsync). Placement blocks detect
// the index dtype themselves (odd-word ballot over 512 samples), so there is
// no intra-kernel ordering dependency at all.
// ---------------------------------------------------------------------------
__global__ __launch_bounds__(256) void mega_kernel(
    const void* __restrict__ src, const void* __restrict__ dst, int nE,
    int* __restrict__ hdr, int* __restrict__ counts, int* __restrict__ buckets,
    int2* __restrict__ ovf,
    const float* __restrict__ Wn, const float* __restrict__ Ws,
    unsigned short* __restrict__ Bt2,
    const float* __restrict__ feat, unsigned short* __restrict__ Fbf,
    int M, int NPB)
{
    const int b = blockIdx.x;
    const int t = threadIdx.x;

    if (b < NPB) {
        // ---------------- placement: 1 edge per thread ----------------
        // dtype self-detect: int32 input -> odd 32-bit words are real indices
        // (virtually surely nonzero in 128 samples/wave); int64 -> hi words 0.
        const int* p32 = (const int*)src;
        const int lane = t & 63;
        const int sbase = (t >> 6) * 64 + lane;          // 0..255 per block
        const int pred = (p32[2 * sbase + 1] | p32[2 * (sbase + 256) + 1]) != 0;
        const bool is32 = (__ballot(pred) != 0ull);

        const int e = b * 256 + t;
        if (e < nE) {
            int s, d;
            if (is32) {
                s = ((const int*)src)[e];
                d = ((const int*)dst)[e];
            } else {
                s = (int)((const long long*)src)[e];
                d = (int)((const long long*)dst)[e];
            }
            int pos = atomicAdd(&counts[d], 1);
            if (pos < CAP) {
                buckets[(size_t)d * CAP + pos] = s;
            } else {
                int oi = atomicAdd(&hdr[1], 1);
                ovf[oi] = make_int2(s, d);
            }
        }
    } else if (b < NPB + 128) {
        // ---------------- Bt2 build: [n][k], k<128 -> Wn, else Ws ----------
        int idx = (b - NPB) * 256 + t;      // 0..32767 over [n][k]
        int n = idx >> 8, k = idx & 255;
        float v = (k < DF) ? Wn[(size_t)k * DF + n]
                           : Ws[(size_t)(k - DF) * DF + n];
        Bt2[idx] = f2bf(v);
    } else {
        // ---------------- feat -> bf16 (+ zero sentinel row M) -------------
        const long long base = ((long long)(b - NPB - 128) * 2048 + t * 8);
        const long long mtot = (long long)M * DF;
        const long long ttot = (long long)(M + 1) * DF;
        if (base + 8 <= mtot) {
            float4 v0 = *reinterpret_cast<const float4*>(feat + base);
            float4 v1 = *reinterpret_cast<const float4*>(feat + base + 4);
            uint4 pk;
            pk.x = pack2(v0.x, v0.y);
            pk.y = pack2(v0.z, v0.w);
            pk.z = pack2(v1.x, v1.y);
            pk.w = pack2(v1.z, v1.w);
            *reinterpret_cast<uint4*>(Fbf + base) = pk;
        } else if (base + 8 <= ttot) {
            *reinterpret_cast<uint4*>(Fbf + base) = make_uint4(0u, 0u, 0u, 0u);
        }
    }
}

// ---------------------------------------------------------------------------
// agg_gemm: per 64-node tile, (1) aggregate neighbor Fbf rows (branch-free
// sentinel bursts, f32 accum) + stage self row -> As[64][Agg|feat] bf16,
// (2) K=256 MFMA: out = [Agg|feat] @ [Wn;Ws] + b, written ONCE.
// As is a flat 32KB buffer with a 16B-unit XOR swizzle (unit ^= row&7):
// exactly 5 blocks/CU (vs 4 with the padded layout) and <=2-way LDS banking
// on both the phase-1 uint4 writes and the ds_read_b128 fragment reads.
// ---------------------------------------------------------------------------
#define ASW(r, u) (((r) << 5) + ((u) ^ ((r) & 7)))

__global__ __launch_bounds__(256) void agg_gemm_kernel(
    const unsigned short* __restrict__ Fbf, const unsigned short* __restrict__ Bt2,
    const float* __restrict__ bias, float* __restrict__ out, int M,
    const int* __restrict__ counts, const int* __restrict__ buckets,
    const int* __restrict__ hdr, const int2* __restrict__ ovf)
{
    __shared__ uint4 As16[GR * 32];   // 64 rows x 32 x 16B = 32 KB, swizzled

    const int t = threadIdx.x;
    const int block_row = blockIdx.x * GR;

    const int wave = t >> 6;
    const int lane = t & 63;
    const int nl   = lane & 15;
    const int quad = lane >> 4;

    // ---- preload B fragments first (independent, L2-hot, arrive under agg) ----
    const int n0 = wave * 32;
    short8 bfrag[2][8];
#pragma unroll
    for (int ct = 0; ct < 2; ct++)
#pragma unroll
        for (int kk = 0; kk < 8; kk++)
            bfrag[ct][kk] = *reinterpret_cast<const short8*>(
                Bt2 + (size_t)(n0 + ct * 16 + nl) * KX + kk * 32 + quad * 8);
    float bcol[2];
#pragma unroll
    for (int ct = 0; ct < 2; ct++)
        bcol[ct] = bias[n0 + ct * 16 + nl];

    // ---- phase 1: aggregate 4 nodes per 16-lane group ----
    {
        const int gi = t >> 4;          // group 0..15
        const int li = t & 15;          // lane in group
        const size_t lo = (size_t)li * 8;   // bf16 elems (16B per lane)
        const int n_ovf = hdr[1];

#define LDF(s) (*reinterpret_cast<const uint4*>(Fbf + (size_t)(s) * DF + lo))
#define ACC8(Y) do { \
        a0 += bf2f((unsigned short)((Y).x)); a1 += bf2f((unsigned short)((Y).x >> 16)); \
        a2 += bf2f((unsigned short)((Y).y)); a3 += bf2f((unsigned short)((Y).y >> 16)); \
        a4 += bf2f((unsigned short)((Y).z)); a5 += bf2f((unsigned short)((Y).z >> 16)); \
        a6 += bf2f((unsigned short)((Y).w)); a7 += bf2f((unsigned short)((Y).w >> 16)); \
    } while (0)

#pragma unroll
        for (int j = 0; j < 4; j++) {
            const int r_local = gi * 4 + j;
            const int grow = block_row + r_local;
            const int deg_raw = (grow < M) ? counts[grow] : 0;
            const int deg = min(deg_raw, CAP);
            const int* b = buckets + (size_t)((grow < M) ? grow : 0) * CAP;

            float a0 = 0.f, a1 = 0.f, a2 = 0.f, a3 = 0.f;
            float a4 = 0.f, a5 = 0.f, a6 = 0.f, a7 = 0.f;

            // slots 0..7, sentinel-selected, unconditional burst
            int4 sa = *reinterpret_cast<const int4*>(b);
            int4 sb = *reinterpret_cast<const int4*>(b + 4);
            const int i0 = (0 < deg) ? sa.x : M;
            const int i1 = (1 < deg) ? sa.y : M;
            const int i2 = (2 < deg) ? sa.z : M;
            const int i3 = (3 < deg) ? sa.w : M;
            const int i4 = (4 < deg) ? sb.x : M;
            const int i5 = (5 < deg) ? sb.y : M;
            const int i6 = (6 < deg) ? sb.z : M;
            const int i7 = (7 < deg) ? sb.w : M;
            uint4 y0 = LDF(i0);
            uint4 y1 = LDF(i1);
            uint4 y2 = LDF(i2);
            uint4 y3 = LDF(i3);
            uint4 y4 = LDF(i4);
            uint4 y5 = LDF(i5);
            uint4 y6 = LDF(i6);
            uint4 y7 = LDF(i7);
            // self row rides in the same burst
            uint4 sf = LDF((grow < M) ? grow : M);
            ACC8(y0); ACC8(y1); ACC8(y2); ACC8(y3);
            ACC8(y4); ACC8(y5); ACC8(y6); ACC8(y7);

            if (deg > 8) {
                int4 sc = *reinterpret_cast<const int4*>(b + 8);
                int4 sd = *reinterpret_cast<const int4*>(b + 12);
                const int j0 = ( 8 < deg) ? sc.x : M;
                const int j1 = ( 9 < deg) ? sc.y : M;
                const int j2 = (10 < deg) ? sc.z : M;
                const int j3 = (11 < deg) ? sc.w : M;
                const int j4 = (12 < deg) ? sd.x : M;
                const int j5 = (13 < deg) ? sd.y : M;
                const int j6 = (14 < deg) ? sd.z : M;
                const int j7 = (15 < deg) ? sd.w : M;
                uint4 z0 = LDF(j0);
                uint4 z1 = LDF(j1);
                uint4 z2 = LDF(j2);
                uint4 z3 = LDF(j3);
                uint4 z4 = LDF(j4);
                uint4 z5 = LDF(j5);
                uint4 z6 = LDF(j6);
                uint4 z7 = LDF(j7);
                ACC8(z0); ACC8(z1); ACC8(z2); ACC8(z3);
                ACC8(z4); ACC8(z5); ACC8(z6); ACC8(z7);
            }

            // rare: overflow edges for this node (list is tiny)
            if (deg_raw > CAP) {
                for (int i = 0; i < n_ovf; i++) {
                    int2 sd2 = ovf[i];
                    if (sd2.y == grow) {
                        uint4 y = LDF(sd2.x);
                        ACC8(y);
                    }
                }
            }

            // write Agg (rounded bf16) and self halves of the swizzled A row
            uint4 pk;
            pk.x = pack2(a0, a1);
            pk.y = pack2(a2, a3);
            pk.z = pack2(a4, a5);
            pk.w = pack2(a6, a7);
            As16[ASW(r_local, li)]      = pk;   // Agg half: units 0..15
            As16[ASW(r_local, 16 + li)] = sf;   // self half: units 16..31
        }
#undef LDF
#undef ACC8
    }

    __syncthreads();

    // ---- phase 2: K=256 MFMA, direct out store (write-once) ----
#pragma unroll
    for (int rt = 0; rt < 4; rt++) {
        const int arow = rt * 16 + nl;
        short8 afrag[8];
#pragma unroll
        for (int kk = 0; kk < 8; kk++)
            afrag[kk] = *reinterpret_cast<const short8*>(
                &As16[ASW(arow, kk * 4 + quad)]);
#pragma unroll
        for (int ct = 0; ct < 2; ct++) {
            v4f acc = {0.f, 0.f, 0.f, 0.f};
#pragma unroll
            for (int kk = 0; kk < 8; kk++)
                acc = __builtin_amdgcn_mfma_f32_16x16x32_bf16(
                    afrag[kk], bfrag[ct][kk], acc, 0, 0, 0);
            const int n = n0 + ct * 16 + nl;
            const int lrow = rt * 16 + quad * 4;
#pragma unroll
            for (int r = 0; r < 4; r++) {
                const int grow = block_row + lrow + r;
                if (grow < M)
                    out[(size_t)grow * DF + n] = acc[r] + bcol[ct];
            }
        }
    }
}

extern "C" void kernel_launch(void* const* d_in, const int* in_sizes, int n_in,
                              void* d_out, int out_size, void* d_ws, size_t ws_size,
                              hipStream_t stream) {
    const float* feat = (const float*)d_in[0];
    const void*  src  = d_in[1];
    const void*  dst  = d_in[2];
    const float* Wn   = (const float*)d_in[3];
    const float* bias = (const float*)d_in[4];
    const float* Wsf  = (const float*)d_in[5];
    float* out = (float*)d_out;

    const int M  = in_sizes[0] / DF;   // 100000
    const int nE = in_sizes[1];        // 600000

    // workspace: [hdr 256B][counts][buckets][Bt2 64KB][Fbf (M+1 rows)][ovf]
    const size_t cnt_off   = 256;
    const size_t cnt_bytes = (((size_t)(M + 64) * 4) + 255) & ~(size_t)255;
    const size_t bkt_off   = cnt_off + cnt_bytes;
    const size_t bkt_bytes = (size_t)M * CAP * sizeof(int);
    const size_t bt_off    = (bkt_off + bkt_bytes + 255) & ~(size_t)255;
    const size_t bt_bytes  = (size_t)DF * KX * sizeof(unsigned short);
    const size_t f_off     = bt_off + bt_bytes;
    const size_t f_bytes   = (size_t)(M + 1) * DF * sizeof(unsigned short);
    const size_t ovf_off   = (f_off + f_bytes + 255) & ~(size_t)255;

    int*            hdr     = (int*)d_ws;
    int*            counts  = (int*)((char*)d_ws + cnt_off);
    int*            buckets = (int*)((char*)d_ws + bkt_off);
    unsigned short* Bt2     = (unsigned short*)((char*)d_ws + bt_off);
    unsigned short* Fbf     = (unsigned short*)((char*)d_ws + f_off);
    int2*           ovf     = (int2*)((char*)d_ws + ovf_off);

    // zero hdr + counts in one contiguous async memset (graph-capturable)
    hipMemsetAsync(d_ws, 0, cnt_off + cnt_bytes, stream);

    const int NPB = (nE + 255) / 256;
    const long long ttot = (long long)(M + 1) * DF;
    const int nconv = (int)((ttot + 2047) / 2048);

    mega_kernel<<<NPB + 128 + nconv, 256, 0, stream>>>(
        src, dst, nE, hdr, counts, buckets, ovf,
        Wn, Wsf, Bt2, feat, Fbf, M, NPB);

    const int gemm_blocks = (M + GR - 1) / GR;
    agg_gemm_kernel<<<gemm_blocks, 256, 0, stream>>>(
        Fbf, Bt2, bias, out, M, counts, buckets, hdr, ovf);
}

// Round 8
// 186.420 us; speedup vs baseline: 1.0679x; 1.0097x over previous
//
#include <hip/hip_runtime.h>

#define DF 128     // feature dim
#define KX 256     // extended GEMM K: [Agg | feat]
#define CAP 16     // bucket capacity per node = one 64B cache line
#define GR 64      // GEMM rows per block

typedef __attribute__((ext_vector_type(8))) short short8;   // 8 bf16 (4 VGPRs)
typedef __attribute__((ext_vector_type(4))) float v4f;      // MFMA accumulator

__device__ __forceinline__ unsigned short f2bf(float x) {
    unsigned u = __float_as_uint(x);
    unsigned r = (u + 0x7FFFu + ((u >> 16) & 1u)) >> 16;    // RNE
    return (unsigned short)r;
}
__device__ __forceinline__ float bf2f(unsigned short h) {
    return __uint_as_float((unsigned)h << 16);
}
__device__ __forceinline__ unsigned pack2(float a, float b) {
    return (unsigned)f2bf(a) | ((unsigned)f2bf(b) << 16);
}

// 16B-unit XOR swizzle for the 32KB A tile (exactly 5 blocks/CU)
#define ASW(r, u) (((r) << 5) + ((u) ^ ((r) & 7)))

__device__ __forceinline__ bool detect_is32(const void* src, int nE, int t) {
    // int32 input -> sampled odd 32-bit words are real node ids (nonzero
    // w.h.p. over 512 samples); int64 -> hi words are 0.
    const int* p32 = (const int*)src;
    const int s0 = (t < nE) ? t : 0;
    const int s1 = (t + 256 < nE) ? t + 256 : 0;
    const int pred = (p32[2 * s0 + 1] | p32[2 * s1 + 1]) != 0;
    return (__ballot(pred) != 0ull);
}

// ---------------------------------------------------------------------------
// mega: one dispatch fusing three independent jobs. Roles are STRIPED across
// blockIdx (every k-th block = placement) so the latency-bound placement and
// the BW-bound conversion are co-resident from the first occupancy wave and
// overlap, instead of serializing phase-by-phase.
//   role 0 (NPB blocks)  : edge placement, 1 edge/thread.
//   role 1 (128 blocks)  : Bt2[n][k] build (128 x 256 bf16 weights^T).
//   role 2 (rest)        : feat f32 -> Fbf bf16 stream + zero sentinel row.
// Requires counts==0 and hdr[1]==0 on entry (per-call memset — the harness
// re-poisons the workspace between iterations, so no state may carry over).
// ---------------------------------------------------------------------------
__global__ __launch_bounds__(256) void mega_kernel(
    const void* __restrict__ src, const void* __restrict__ dst, int nE,
    int* __restrict__ hdr, int* __restrict__ counts, int* __restrict__ buckets,
    int2* __restrict__ ovf,
    const float* __restrict__ Wn, const float* __restrict__ Ws,
    unsigned short* __restrict__ Bt2,
    const float* __restrict__ feat, unsigned short* __restrict__ Fbf,
    int M, int NPB, int kstripe)
{
    const int b = blockIdx.x;
    const int t = threadIdx.x;

    // ---- role decode: placement striped at every kstripe-th index ----
    int pid = -1, j = 0;
    {
        const int q = b / kstripe;
        if ((b % kstripe) == 0 && q < NPB) {
            pid = q;                                   // placement block id
        } else {
            const int placed_before = min(NPB, q + ((b % kstripe) ? 1 : 0));
            j = b - placed_before;                     // non-place job id
        }
    }

    if (pid >= 0) {
        // ---------------- placement: 1 edge per thread ----------------
        const bool is32 = detect_is32(src, nE, t);
        const int e = pid * 256 + t;
        if (e < nE) {
            int s, d;
            if (is32) {
                s = ((const int*)src)[e];
                d = ((const int*)dst)[e];
            } else {
                s = (int)((const long long*)src)[e];
                d = (int)((const long long*)dst)[e];
            }
            int pos = atomicAdd(&counts[d], 1);
            if (pos < CAP) {
                buckets[(size_t)d * CAP + pos] = s;
            } else {
                int oi = atomicAdd(&hdr[1], 1);
                ovf[oi] = make_int2(s, d);
            }
        }
    } else if (j < 128) {
        // ---------------- Bt2 build: [n][k], k<128 -> Wn, else Ws ----------
        int idx = j * 256 + t;              // 0..32767 over [n][k]
        int n = idx >> 8, k = idx & 255;
        float v = (k < DF) ? Wn[(size_t)k * DF + n]
                           : Ws[(size_t)(k - DF) * DF + n];
        Bt2[idx] = f2bf(v);
    } else {
        // ---------------- feat -> bf16 (+ zero sentinel row M) -------------
        const long long base = ((long long)(j - 128) * 2048 + t * 8);
        const long long mtot = (long long)M * DF;
        const long long ttot = (long long)(M + 1) * DF;
        if (base + 8 <= mtot) {
            float4 v0 = *reinterpret_cast<const float4*>(feat + base);
            float4 v1 = *reinterpret_cast<const float4*>(feat + base + 4);
            uint4 pk;
            pk.x = pack2(v0.x, v0.y);
            pk.y = pack2(v0.z, v0.w);
            pk.z = pack2(v1.x, v1.y);
            pk.w = pack2(v1.z, v1.w);
            *reinterpret_cast<uint4*>(Fbf + base) = pk;
        } else if (base + 8 <= ttot) {
            *reinterpret_cast<uint4*>(Fbf + base) = make_uint4(0u, 0u, 0u, 0u);
        }
    }
}

// ---------------------------------------------------------------------------
// agg_gemm: per 64-node tile, (1) aggregate neighbor Fbf rows (branch-free
// sentinel bursts, f32 accum) + stage self row -> swizzled As (32KB),
// (2) K=256 MFMA: out = [Agg|feat] @ [Wn;Ws] + b, written ONCE.
// (verbatim round-5 kernel: 60.3us, FETCH 81.6MB, WRITE 50.0MB)
// ---------------------------------------------------------------------------
__global__ __launch_bounds__(256) void agg_gemm_kernel(
    const unsigned short* __restrict__ Fbf, const unsigned short* __restrict__ Bt2,
    const float* __restrict__ bias, float* __restrict__ out, int M,
    const int* __restrict__ counts, const int* __restrict__ buckets,
    const int* __restrict__ hdr, const int2* __restrict__ ovf)
{
    __shared__ uint4 As16[GR * 32];   // 64 rows x 32 x 16B = 32 KB, swizzled

    const int t = threadIdx.x;
    const int block_row = blockIdx.x * GR;

    const int wave = t >> 6;
    const int lane = t & 63;
    const int nl   = lane & 15;
    const int quad = lane >> 4;

    // ---- preload B fragments (independent, L2-hot, arrive under agg) ----
    const int n0 = wave * 32;
    short8 bfrag[2][8];
#pragma unroll
    for (int ct = 0; ct < 2; ct++)
#pragma unroll
        for (int kk = 0; kk < 8; kk++)
            bfrag[ct][kk] = *reinterpret_cast<const short8*>(
                Bt2 + (size_t)(n0 + ct * 16 + nl) * KX + kk * 32 + quad * 8);
    float bcol[2];
#pragma unroll
    for (int ct = 0; ct < 2; ct++)
        bcol[ct] = bias[n0 + ct * 16 + nl];

    // ---- phase 1: aggregate 4 nodes per 16-lane group ----
    {
        const int gi = t >> 4;
        const int li = t & 15;
        const size_t lo = (size_t)li * 8;
        const int n_ovf = hdr[1];

#define LDF(s) (*reinterpret_cast<const uint4*>(Fbf + (size_t)(s) * DF + lo))
#define ACC8(Y) do { \
        a0 += bf2f((unsigned short)((Y).x)); a1 += bf2f((unsigned short)((Y).x >> 16)); \
        a2 += bf2f((unsigned short)((Y).y)); a3 += bf2f((unsigned short)((Y).y >> 16)); \
        a4 += bf2f((unsigned short)((Y).z)); a5 += bf2f((unsigned short)((Y).z >> 16)); \
        a6 += bf2f((unsigned short)((Y).w)); a7 += bf2f((unsigned short)((Y).w >> 16)); \
    } while (0)

#pragma unroll
        for (int j = 0; j < 4; j++) {
            const int r_local = gi * 4 + j;
            const int grow = block_row + r_local;
            const int deg_raw = (grow < M) ? counts[grow] : 0;
            const int deg = min(deg_raw, CAP);
            const int* b = buckets + (size_t)((grow < M) ? grow : 0) * CAP;

            float a0 = 0.f, a1 = 0.f, a2 = 0.f, a3 = 0.f;
            float a4 = 0.f, a5 = 0.f, a6 = 0.f, a7 = 0.f;

            int4 sa = *reinterpret_cast<const int4*>(b);
            int4 sb = *reinterpret_cast<const int4*>(b + 4);
            const int i0 = (0 < deg) ? sa.x : M;
            const int i1 = (1 < deg) ? sa.y : M;
            const int i2 = (2 < deg) ? sa.z : M;
            const int i3 = (3 < deg) ? sa.w : M;
            const int i4 = (4 < deg) ? sb.x : M;
            const int i5 = (5 < deg) ? sb.y : M;
            const int i6 = (6 < deg) ? sb.z : M;
            const int i7 = (7 < deg) ? sb.w : M;
            uint4 y0 = LDF(i0);
            uint4 y1 = LDF(i1);
            uint4 y2 = LDF(i2);
            uint4 y3 = LDF(i3);
            uint4 y4 = LDF(i4);
            uint4 y5 = LDF(i5);
            uint4 y6 = LDF(i6);
            uint4 y7 = LDF(i7);
            uint4 sf = LDF((grow < M) ? grow : M);
            ACC8(y0); ACC8(y1); ACC8(y2); ACC8(y3);
            ACC8(y4); ACC8(y5); ACC8(y6); ACC8(y7);

            if (deg > 8) {
                int4 sc = *reinterpret_cast<const int4*>(b + 8);
                int4 sd = *reinterpret_cast<const int4*>(b + 12);
                const int j0 = ( 8 < deg) ? sc.x : M;
                const int j1 = ( 9 < deg) ? sc.y : M;
                const int j2 = (10 < deg) ? sc.z : M;
                const int j3 = (11 < deg) ? sc.w : M;
                const int j4 = (12 < deg) ? sd.x : M;
                const int j5 = (13 < deg) ? sd.y : M;
                const int j6 = (14 < deg) ? sd.z : M;
                const int j7 = (15 < deg) ? sd.w : M;
                uint4 z0 = LDF(j0);
                uint4 z1 = LDF(j1);
                uint4 z2 = LDF(j2);
                uint4 z3 = LDF(j3);
                uint4 z4 = LDF(j4);
                uint4 z5 = LDF(j5);
                uint4 z6 = LDF(j6);
                uint4 z7 = LDF(j7);
                ACC8(z0); ACC8(z1); ACC8(z2); ACC8(z3);
                ACC8(z4); ACC8(z5); ACC8(z6); ACC8(z7);
            }

            if (deg_raw > CAP) {   // rare overflow edges for this node
                for (int i = 0; i < n_ovf; i++) {
                    int2 sd2 = ovf[i];
                    if (sd2.y == grow) {
                        uint4 y = LDF(sd2.x);
                        ACC8(y);
                    }
                }
            }

            uint4 pk;
            pk.x = pack2(a0, a1);
            pk.y = pack2(a2, a3);
            pk.z = pack2(a4, a5);
            pk.w = pack2(a6, a7);
            As16[ASW(r_local, li)]      = pk;   // Agg half
            As16[ASW(r_local, 16 + li)] = sf;   // self half
        }
#undef LDF
#undef ACC8
    }

    __syncthreads();

    // ---- phase 2: K=256 MFMA, direct out store (write-once) ----
#pragma unroll
    for (int rt = 0; rt < 4; rt++) {
        const int arow = rt * 16 + nl;
        short8 afrag[8];
#pragma unroll
        for (int kk = 0; kk < 8; kk++)
            afrag[kk] = *reinterpret_cast<const short8*>(
                &As16[ASW(arow, kk * 4 + quad)]);
#pragma unroll
        for (int ct = 0; ct < 2; ct++) {
            v4f acc = {0.f, 0.f, 0.f, 0.f};
#pragma unroll
            for (int kk = 0; kk < 8; kk++)
                acc = __builtin_amdgcn_mfma_f32_16x16x32_bf16(
                    afrag[kk], bfrag[ct][kk], acc, 0, 0, 0);
            const int n = n0 + ct * 16 + nl;
            const int lrow = rt * 16 + quad * 4;
#pragma unroll
            for (int r = 0; r < 4; r++) {
                const int grow = block_row + lrow + r;
                if (grow < M)
                    out[(size_t)grow * DF + n] = acc[r] + bcol[ct];
            }
        }
    }
}

extern "C" void kernel_launch(void* const* d_in, const int* in_sizes, int n_in,
                              void* d_out, int out_size, void* d_ws, size_t ws_size,
                              hipStream_t stream) {
    const float* feat = (const float*)d_in[0];
    const void*  src  = d_in[1];
    const void*  dst  = d_in[2];
    const float* Wn   = (const float*)d_in[3];
    const float* bias = (const float*)d_in[4];
    const float* Wsf  = (const float*)d_in[5];
    float* out = (float*)d_out;

    const int M  = in_sizes[0] / DF;   // 100000
    const int nE = in_sizes[1];        // 600000

    // workspace: [hdr 256B][counts][buckets][Bt2 64KB][Fbf (M+1 rows)][ovf]
    const size_t cnt_off   = 256;
    const size_t cnt_bytes = (((size_t)(M + 64) * 4) + 255) & ~(size_t)255;
    const size_t bkt_off   = cnt_off + cnt_bytes;
    const size_t bkt_bytes = (size_t)M * CAP * sizeof(int);
    const size_t bt_off    = (bkt_off + bkt_bytes + 255) & ~(size_t)255;
    const size_t bt_bytes  = (size_t)DF * KX * sizeof(unsigned short);
    const size_t f_off     = bt_off + bt_bytes;
    const size_t f_bytes   = (size_t)(M + 1) * DF * sizeof(unsigned short);
    const size_t ovf_off   = (f_off + f_bytes + 255) & ~(size_t)255;

    int*            hdr     = (int*)d_ws;
    int*            counts  = (int*)((char*)d_ws + cnt_off);
    int*            buckets = (int*)((char*)d_ws + bkt_off);
    unsigned short* Bt2     = (unsigned short*)((char*)d_ws + bt_off);
    unsigned short* Fbf     = (unsigned short*)((char*)d_ws + f_off);
    int2*           ovf     = (int2*)((char*)d_ws + ovf_off);

    // per-call zero of hdr+counts (workspace is re-poisoned between calls)
    hipMemsetAsync(d_ws, 0, cnt_off + cnt_bytes, stream);

    const int NPB = (nE + 255) / 256;
    const long long ttot = (long long)(M + 1) * DF;
    const int nconv = (int)((ttot + 2047) / 2048);
    const int total = NPB + 128 + nconv;
    const int kstripe = total / NPB;   // >=1; stripes placement across grid

    mega_kernel<<<total, 256, 0, stream>>>(
        src, dst, nE, hdr, counts, buckets, ovf,
        Wn, Wsf, Bt2, feat, Fbf, M, NPB, kstripe);

    const int gemm_blocks = (M + GR - 1) / GR;
    agg_gemm_kernel<<<gemm_blocks, 256, 0, stream>>>(
        Fbf, Bt2, bias, out, M, counts, buckets, hdr, ovf);
}